// Round 7
// baseline (329.423 us; speedup 1.0000x reference)
//
#include <hip/hip_runtime.h>
#include <hip/hip_bf16.h>
#include <stdint.h>

// Problem constants
constexpr int NB = 8;     // batch
constexpr int NS = 1024;  // seq
constexpr int ND = 1024;  // model dim
constexpr int NH = 16;    // heads
constexpr int NDK = 64;   // head dim
constexpr int NT = NS / 64;  // 16 q-tiles of 64 rows
constexpr int NKT = ND / 64; // 16 K-tiles per GEMM (K=1024 fixed)

typedef __bf16 bf16_t;
typedef __attribute__((ext_vector_type(8))) __bf16 bf16x8;
typedef __attribute__((ext_vector_type(4))) __bf16 bf16x4;
typedef __attribute__((ext_vector_type(4))) float f32x4;

#define GLL16(g, s) __builtin_amdgcn_global_load_lds( \
    (const __attribute__((address_space(1))) void*)(g), \
    (__attribute__((address_space(3))) void*)(s), 16, 0, 0)

// ---------------- fp32 -> bf16 converts (fused launches) ----------------
__device__ __forceinline__ void cvt_body(const float* __restrict__ s,
                                         bf16_t* __restrict__ d, long n) {
  long i0 = (long)(blockIdx.x * blockDim.x + threadIdx.x) * 4;
  long step = (long)gridDim.x * blockDim.x * 4;
  for (long i = i0; i < n; i += step) {
    float4 f = *(const float4*)(s + i);
    bf16x4 o;
    o[0] = (bf16_t)f.x; o[1] = (bf16_t)f.y; o[2] = (bf16_t)f.z; o[3] = (bf16_t)f.w;
    *(bf16x4*)(d + i) = o;
  }
}

__global__ __launch_bounds__(256) void cvt3_kernel(const float* s0, bf16_t* d0,
                                                   const float* s1, bf16_t* d1,
                                                   const float* s2, bf16_t* d2, long n) {
  const float* s = blockIdx.y == 0 ? s0 : blockIdx.y == 1 ? s1 : s2;
  bf16_t* d = blockIdx.y == 0 ? d0 : blockIdx.y == 1 ? d1 : d2;
  cvt_body(s, d, n);
}

__global__ __launch_bounds__(256) void cvt4_kernel(const float* s0, bf16_t* d0,
                                                   const float* s1, bf16_t* d1,
                                                   const float* s2, bf16_t* d2,
                                                   const float* s3, bf16_t* d3, long n) {
  const float* s = blockIdx.y == 0 ? s0 : blockIdx.y == 1 ? s1 : blockIdx.y == 2 ? s2 : s3;
  bf16_t* d = blockIdx.y == 0 ? d0 : blockIdx.y == 1 ? d1 : blockIdx.y == 2 ? d2 : d3;
  cvt_body(s, d, n);
}

// ---------------- GEMM: C[M,N] = A[M,K] @ W[N,K]^T + bias ----------------
// 128x128 tile, 4 waves (2M x 2N, per-wave 64x64), BK=64, mfma 16x16x32.
// A-operand: direct global->register prefetch (per-lane contiguous 16B; no
// LDS round-trip; re-reads served by XCD-local L2). B-operand: LDS
// triple-buffer (3 x 16KB = 48KB -> 3 blocks/CU for cross-block slip),
// XOR-swizzled rows + pre-swizzled GLL source (0 conflicts, proven R3+).
// Counted vmcnt ledger (issue order pinned by sched_barrier): per iter issue
// A(t+1):8 then B-GLL(t+2):4; steady wait vmcnt(16) retires exactly
// B(t)+A(t); tails 12/0. Trailing lgkmcnt(0)+barrier protects buffer reuse.
template<bool OUT_F32>
__device__ __forceinline__ void gemm_body(bf16_t* S,
                                          const bf16_t* __restrict__ A,
                                          const bf16_t* __restrict__ W,
                                          const float* __restrict__ bias,
                                          void* __restrict__ Cout,
                                          int bx, int by) {
  const int tid = threadIdx.x;           // 0..255
  const int l = tid & 63, w = tid >> 6;  // 4 waves
  const int wr = w >> 1, wc = w & 1;     // 2M x 2N
  const int g = l >> 4, r = l & 15;
  const int m0 = by * 128, n0 = bx * 128;
  const int wbase = w * 512;             // wave-uniform LDS base (elements)

  const bf16_t* abase = A + (size_t)(m0 + wr * 64 + r) * ND;

  auto stageB = [&](int q, int t) {
#pragma unroll
    for (int it = 0; it < 4; ++it) {     // B: 128 rows x 8 chunks, 16KB
      int idx = it * 256 + tid;
      int row = idx >> 3, c = (idx & 7) ^ (row & 7);
      GLL16(W + (size_t)(n0 + row) * ND + (t << 6) + c * 8,
            S + q * 8192 + it * 2048 + wbase);
    }
  };

  auto loadA = [&](bf16x8 (&dst)[8], int t) {
#pragma unroll
    for (int kk = 0; kk < 2; ++kk)
#pragma unroll
      for (int m = 0; m < 4; ++m)
        dst[kk * 4 + m] = *(const bf16x8*)(abase + (size_t)m * 16 * ND + t * 64 + kk * 32 + g * 8);
  };

  f32x4 acc[4][4] = {};
  bf16x8 aA[8], aB[8];

  // prologue (ledger: B0:4, B1:4, A0:8 in flight)
  stageB(0, 0);
  stageB(1, 1);
  loadA(aA, 0);

  auto body = [&](int t, int q, bf16x8 (&cur)[8], bf16x8 (&nxt)[8]) {
    int q2 = q + 2; if (q2 >= 3) q2 -= 3;
    if (t + 1 < NKT) loadA(nxt, t + 1);
    __builtin_amdgcn_sched_barrier(0);   // pin issue order: A(t+1) before B(t+2)
    if (t + 2 < NKT) stageB(q2, t + 2);
    __builtin_amdgcn_sched_barrier(0);
    // queue (oldest->newest): B(t):4, A(t):8, B(t+1):4, A(t+1):8, B(t+2):4
    if (t + 2 < NKT)      asm volatile("s_waitcnt vmcnt(16)" ::: "memory");
    else if (t + 1 < NKT) asm volatile("s_waitcnt vmcnt(12)" ::: "memory");
    else                  asm volatile("s_waitcnt vmcnt(0)" ::: "memory");
    __builtin_amdgcn_s_barrier();        // B tile t visible to all waves

    const bf16_t* b_ = S + q * 8192;
#pragma unroll
    for (int kk = 0; kk < 2; ++kk) {
      bf16x8 bw[4];
#pragma unroll
      for (int n = 0; n < 4; ++n) {
        int row = wc * 64 + n * 16 + r;
        bw[n] = *(const bf16x8*)(b_ + row * 64 + (((kk * 4 + g) ^ (row & 7)) << 3));
      }
      __builtin_amdgcn_s_setprio(1);
#pragma unroll
      for (int m = 0; m < 4; ++m)
#pragma unroll
        for (int n = 0; n < 4; ++n)
          acc[m][n] = __builtin_amdgcn_mfma_f32_16x16x32_bf16(cur[kk * 4 + m], bw[n], acc[m][n], 0, 0, 0);
      __builtin_amdgcn_s_setprio(0);
    }
    asm volatile("s_waitcnt lgkmcnt(0)" ::: "memory");
    __builtin_amdgcn_s_barrier();        // readers done before buf q restaged
  };

  int q = 0;
#pragma unroll 1
  for (int tt = 0; tt < NKT; tt += 2) {  // parity-unrolled: static cur/nxt
    body(tt, q, aA, aB);     ++q; if (q >= 3) q -= 3;
    body(tt + 1, q, aB, aA); ++q; if (q >= 3) q -= 3;
  }

#pragma unroll
  for (int n = 0; n < 4; ++n) {
    int col = n0 + wc * 64 + n * 16 + r;
    float bv = bias[col];
#pragma unroll
    for (int m = 0; m < 4; ++m) {
      int row0 = m0 + wr * 64 + m * 16 + g * 4;
#pragma unroll
      for (int j = 0; j < 4; ++j) {
        float vv = acc[m][n][j] + bv;
        if (OUT_F32)
          ((float*)Cout)[(size_t)(row0 + j) * ND + col] = vv;
        else
          ((bf16_t*)Cout)[(size_t)(row0 + j) * ND + col] = (bf16_t)vv;
      }
    }
  }
}

// O-projection: grid 512, XCD-grouped bijective swizzle.
__global__ __launch_bounds__(256, 3) void gemm_bt(const bf16_t* __restrict__ A,
                                                  const bf16_t* __restrict__ W,
                                                  const float* __restrict__ bias,
                                                  float* __restrict__ Cout) {
  __shared__ bf16_t S[3 * 8192];
  const int o = blockIdx.x;
  const int xcd = o & 7, s = o >> 3;   // s in [0,64)
  const int bx = s & 7, u = s >> 3;    // u in [0,8)
  const int by = xcd + 8 * u;          // all bx of one by share an XCD
  gemm_body<true>(S, A, W, bias, (void*)Cout, bx, by);
}

// QKV: grid 1536 = 2 rounds at 3 blocks/CU; XCD-grouped (A-panel + W stay
// L2-resident per XCD).
__global__ __launch_bounds__(256, 3) void gemm_qkv(
    const bf16_t* A0, const bf16_t* W0, const float* b0, bf16_t* C0,
    const bf16_t* A1, const bf16_t* W1, const float* b1, bf16_t* C1,
    const bf16_t* A2, const bf16_t* W2, const float* b2, bf16_t* C2) {
  __shared__ bf16_t S[3 * 8192];
  const int o = blockIdx.x;
  const int xcd = o & 7, s = o >> 3;   // s in [0,192)
  const int bx = s & 7, u = s >> 3;    // u in [0,24)
  const int zby = xcd + 8 * u;         // 0..191
  const int z = zby >> 6, by = zby & 63;
  const bf16_t* A = z == 0 ? A0 : z == 1 ? A1 : A2;
  const bf16_t* W = z == 0 ? W0 : z == 1 ? W1 : W2;
  const float* bb = z == 0 ? b0 : z == 1 ? b1 : b2;
  bf16_t* C = z == 0 ? C0 : z == 1 ? C1 : C2;
  gemm_body<false>(S, A, W, bb, (void*)C, bx, by);
}

// ---------------- causal flash attention (2-phase, swapped QK^T) ----------
// (unchanged from R5 — ~50 µs; see R5 notes)
__global__ __launch_bounds__(256, 4) void attn_kernel(const bf16_t* __restrict__ Q1,
                                                      const bf16_t* __restrict__ K1,
                                                      const bf16_t* __restrict__ V1,
                                                      bf16_t* __restrict__ attn) {
  __shared__ bf16_t Kt[2][64 * 64];
  __shared__ bf16_t Vt[2][64 * 64];
  __shared__ bf16_t Pl[4][16 * 64];

  const int tid = threadIdx.x;
  const int l = tid & 63, w = tid >> 6;
  const int g = l >> 4, r = l & 15;

  const int o = blockIdx.x;
  const int os = (o & 7) * 128 + (o >> 3);
  const int pair = os & 7, hb = os >> 3;
  const int h = hb & 15, b = hb >> 4;

  constexpr float SC = 0.18033688011112042f;  // 0.125 * log2(e)

  for (int ph = 0; ph < 2; ++ph) {
    const int qt = ph ? (NT - 1 - pair) : pair;
    const int qrow_g = qt * 64 + w * 16 + r;

    const bf16_t* qptr = Q1 + ((size_t)b * NS + qrow_g) * ND + h * 64;
    bf16x8 qf0 = *(const bf16x8*)(qptr + g * 8);
    bf16x8 qf1 = *(const bf16x8*)(qptr + 32 + g * 8);
#pragma unroll
    for (int i = 0; i < 8; ++i) {
      qf0[i] = (bf16_t)((float)qf0[i] * SC);
      qf1[i] = (bf16_t)((float)qf1[i] * SC);
    }

    float mrun = -1e30f, lrun = 0.f;
    f32x4 oacc[4] = {};

    __syncthreads();

    bf16x8 vr0, vr1;
    {
#pragma unroll
      for (int it = 0; it < 2; ++it) {
        int idx = it * 256 + tid;
        int key = idx >> 3;
        int dkg = ((idx & 7) ^ (key & 7)) << 3;
        GLL16(K1 + ((size_t)b * NS + key) * ND + h * 64 + dkg,
              &Kt[0][(it * 256 + w * 64) * 8]);
      }
      vr0 = *(const bf16x8*)(V1 + ((size_t)b * NS + l) * ND + h * 64 + w * 8);
      vr1 = *(const bf16x8*)(V1 + ((size_t)b * NS + l) * ND + h * 64 + (4 + w) * 8);
    }

    for (int kt = 0; kt <= qt; ++kt) {
      const int p = kt & 1;
      const int k0 = kt * 64;

#pragma unroll
      for (int it = 0; it < 2; ++it) {
        int dkb = (it * 4 + w) * 8;
#pragma unroll
        for (int jj = 0; jj < 8; ++jj) {
          int dk = dkb + jj;
          int boff = dk * 128 + ((l * 2) ^ ((dk & 7) << 4));
          *(bf16_t*)((char*)Vt[p] + boff) = (it ? vr1 : vr0)[jj];
        }
      }
      __syncthreads();

      if (kt < qt) {
        const int k0n = k0 + 64;
#pragma unroll
        for (int it = 0; it < 2; ++it) {
          int idx = it * 256 + tid;
          int key = idx >> 3;
          int dkg = ((idx & 7) ^ (key & 7)) << 3;
          GLL16(K1 + ((size_t)b * NS + k0n + key) * ND + h * 64 + dkg,
                &Kt[p ^ 1][(it * 256 + w * 64) * 8]);
        }
        vr0 = *(const bf16x8*)(V1 + ((size_t)b * NS + k0n + l) * ND + h * 64 + w * 8);
        vr1 = *(const bf16x8*)(V1 + ((size_t)b * NS + k0n + l) * ND + h * 64 + (4 + w) * 8);
      }

      f32x4 sacc[4] = {};
      __builtin_amdgcn_s_setprio(1);
#pragma unroll
      for (int n = 0; n < 4; ++n) {
        int key = n * 16 + r;
#pragma unroll
        for (int kk = 0; kk < 2; ++kk) {
          int dk2 = kk * 32 + g * 8;
          int boff = key * 128 + ((dk2 * 2) ^ ((key & 7) << 4));
          bf16x8 kf = *(const bf16x8*)((char*)Kt[p] + boff);
          sacc[n] = __builtin_amdgcn_mfma_f32_16x16x32_bf16(kf, kk == 0 ? qf0 : qf1, sacc[n], 0, 0, 0);
        }
      }
      __builtin_amdgcn_s_setprio(0);

      if (kt == qt) {
#pragma unroll
        for (int n = 0; n < 4; ++n)
#pragma unroll
          for (int j = 0; j < 4; ++j)
            if (k0 + n * 16 + g * 4 + j > qrow_g) sacc[n][j] = -1e30f;
      }

      float mx;
      {
        float t0 = fmaxf(fmaxf(sacc[0][0], sacc[0][1]), fmaxf(sacc[0][2], sacc[0][3]));
        float t1 = fmaxf(fmaxf(sacc[1][0], sacc[1][1]), fmaxf(sacc[1][2], sacc[1][3]));
        float t2 = fmaxf(fmaxf(sacc[2][0], sacc[2][1]), fmaxf(sacc[2][2], sacc[2][3]));
        float t3 = fmaxf(fmaxf(sacc[3][0], sacc[3][1]), fmaxf(sacc[3][2], sacc[3][3]));
        mx = fmaxf(fmaxf(t0, t1), fmaxf(t2, t3));
      }
      mx = fmaxf(mx, __shfl_xor(mx, 16));
      mx = fmaxf(mx, __shfl_xor(mx, 32));

      if (!__all(mx <= mrun + 8.0f)) {
        float m_new = fmaxf(mrun, mx);
        float esc = __builtin_amdgcn_exp2f(mrun - m_new);
        mrun = m_new;
        lrun *= esc;
#pragma unroll
        for (int n = 0; n < 4; ++n)
#pragma unroll
          for (int j = 0; j < 4; ++j) oacc[n][j] *= esc;
      }

      float rsum = 0.f;
#pragma unroll
      for (int n = 0; n < 4; ++n) {
        bf16x4 p4;
#pragma unroll
        for (int j = 0; j < 4; ++j) {
          float pe = __builtin_amdgcn_exp2f(sacc[n][j] - mrun);
          rsum += pe;
          p4[j] = (bf16_t)pe;
        }
        *(bf16x4*)((char*)Pl[w] + r * 128 + ((n * 32 + g * 8) ^ ((r & 7) << 4))) = p4;
      }
      rsum += __shfl_xor(rsum, 16);
      rsum += __shfl_xor(rsum, 32);
      lrun += rsum;

      __builtin_amdgcn_s_setprio(1);
#pragma unroll
      for (int kk = 0; kk < 2; ++kk) {
        bf16x8 pf = *(const bf16x8*)((char*)Pl[w] + r * 128 + ((kk * 64 + g * 16) ^ ((r & 7) << 4)));
#pragma unroll
        for (int n = 0; n < 4; ++n) {
          int dkr = n * 16 + r;
          bf16x8 vf = *(const bf16x8*)((char*)Vt[p] + dkr * 128 + ((kk * 64 + g * 16) ^ ((r & 7) << 4)));
          oacc[n] = __builtin_amdgcn_mfma_f32_16x16x32_bf16(vf, pf, oacc[n], 0, 0, 0);
        }
      }
      __builtin_amdgcn_s_setprio(0);
    }  // kt

    float linv = 1.0f / lrun;
#pragma unroll
    for (int n = 0; n < 4; ++n) {
      bf16x4 o4;
#pragma unroll
      for (int j = 0; j < 4; ++j) o4[j] = (bf16_t)(oacc[n][j] * linv);
      *(bf16x4*)(attn + ((size_t)b * NS + qrow_g) * ND + h * 64 + n * 16 + g * 4) = o4;
    }
  }  // ph
}

// ---------------- launch ----------------
extern "C" void kernel_launch(void* const* d_in, const int* in_sizes, int n_in,
                              void* d_out, int out_size, void* d_ws, size_t ws_size,
                              hipStream_t stream) {
  const float* q  = (const float*)d_in[0];
  const float* k  = (const float*)d_in[1];
  const float* v  = (const float*)d_in[2];
  // d_in[3] = mask (int32 tril, implemented analytically)
  const float* Wq = (const float*)d_in[4];
  const float* bq = (const float*)d_in[5];
  const float* Wk = (const float*)d_in[6];
  const float* bk = (const float*)d_in[7];
  const float* Wv = (const float*)d_in[8];
  const float* bv = (const float*)d_in[9];
  const float* Wo = (const float*)d_in[10];
  const float* bo = (const float*)d_in[11];
  float* out = (float*)d_out;

  const size_t NX = (size_t)NB * NS * ND;  // 8388608
  const size_t NW = (size_t)ND * ND;       // 1048576
  char* ws = (char*)d_ws;
  size_t off = 0;
  auto alloc = [&](size_t bytes) {
    char* p = ws + off;
    off += (bytes + 255) & ~(size_t)255;
    return p;
  };
  bf16_t* xq  = (bf16_t*)alloc(NX * 2);
  bf16_t* xk  = (bf16_t*)alloc(NX * 2);
  bf16_t* xv  = (bf16_t*)alloc(NX * 2);
  bf16_t* wqb = (bf16_t*)alloc(NW * 2);
  bf16_t* wkb = (bf16_t*)alloc(NW * 2);
  bf16_t* wvb = (bf16_t*)alloc(NW * 2);
  bf16_t* wob = (bf16_t*)alloc(NW * 2);
  bf16_t* q1  = (bf16_t*)alloc(NX * 2);
  bf16_t* k1  = (bf16_t*)alloc(NX * 2);
  bf16_t* v1  = (bf16_t*)alloc(NX * 2);
  bf16_t* at  = xq;  // xq dead after QKV GEMMs; reuse for attn output

  dim3 blk(256);
  cvt3_kernel<<<dim3(1024, 3), blk, 0, stream>>>(q, xq, k, xk, v, xv, (long)NX);
  cvt4_kernel<<<dim3(128, 4), blk, 0, stream>>>(Wq, wqb, Wk, wkb, Wv, wvb, Wo, wob, (long)NW);

  gemm_qkv<<<dim3(1536), blk, 0, stream>>>(
      xq, wqb, bq, q1, xk, wkb, bk, k1, xv, wvb, bv, v1);

  attn_kernel<<<dim3((NT / 2) * NH * NB), blk, 0, stream>>>(q1, k1, v1, at);

  gemm_bt<<<dim3(512), blk, 0, stream>>>(at, wob, bo, out);
}

// Round 8
// 158.278 us; speedup vs baseline: 2.0813x; 2.0813x over previous
//
#include <hip/hip_runtime.h>
#include <hip/hip_bf16.h>
#include <stdint.h>

// Problem constants
constexpr int NB = 8;     // batch
constexpr int NS = 1024;  // seq
constexpr int ND = 1024;  // model dim
constexpr int NH = 16;    // heads
constexpr int NDK = 64;   // head dim
constexpr int NT = NS / 64;  // 16 q-tiles of 64 rows

typedef __bf16 bf16_t;
typedef __attribute__((ext_vector_type(8))) __bf16 bf16x8;
typedef __attribute__((ext_vector_type(4))) __bf16 bf16x4;
typedef __attribute__((ext_vector_type(4))) float f32x4;

#define GLL16(g, s) __builtin_amdgcn_global_load_lds( \
    (const __attribute__((address_space(1))) void*)(g), \
    (__attribute__((address_space(3))) void*)(s), 16, 0, 0)

// ---------------- fp32 -> bf16 converts (fused launches) ----------------
__device__ __forceinline__ void cvt_body(const float* __restrict__ s,
                                         bf16_t* __restrict__ d, long n) {
  long i0 = (long)(blockIdx.x * blockDim.x + threadIdx.x) * 4;
  long step = (long)gridDim.x * blockDim.x * 4;
  for (long i = i0; i < n; i += step) {
    float4 f = *(const float4*)(s + i);
    bf16x4 o;
    o[0] = (bf16_t)f.x; o[1] = (bf16_t)f.y; o[2] = (bf16_t)f.z; o[3] = (bf16_t)f.w;
    *(bf16x4*)(d + i) = o;
  }
}

__global__ __launch_bounds__(256) void cvt3_kernel(const float* s0, bf16_t* d0,
                                                   const float* s1, bf16_t* d1,
                                                   const float* s2, bf16_t* d2, long n) {
  const float* s = blockIdx.y == 0 ? s0 : blockIdx.y == 1 ? s1 : s2;
  bf16_t* d = blockIdx.y == 0 ? d0 : blockIdx.y == 1 ? d1 : d2;
  cvt_body(s, d, n);
}

__global__ __launch_bounds__(256) void cvt4_kernel(const float* s0, bf16_t* d0,
                                                   const float* s1, bf16_t* d1,
                                                   const float* s2, bf16_t* d2,
                                                   const float* s3, bf16_t* d3, long n) {
  const float* s = blockIdx.y == 0 ? s0 : blockIdx.y == 1 ? s1 : blockIdx.y == 2 ? s2 : s3;
  bf16_t* d = blockIdx.y == 0 ? d0 : blockIdx.y == 1 ? d1 : blockIdx.y == 2 ? d2 : d3;
  cvt_body(s, d, n);
}

// ---------------- GEMM: C[M,N] = A[M,K] @ W[N,K]^T + bias ----------------
// R6 data layout (proven): 256x128 tile, 8 waves (4M x 2N, per-wave 64x64),
// BK=64, triple-buffered LDS (A 32KB + B 16KB per buffer, 144KB total,
// 1 block/CU), GLL16 staging with XOR-swizzled rows + pre-swizzled source
// (0 bank conflicts). NEW (m201/T3+T4 port): 4 fine phases per K-tile, each
// {ds_read subtile + 1-2 GLLs of tile t+2 -> s_barrier -> lgkmcnt(0) +
// sched_barrier (rule 18) -> setprio(1) 8 MFMA setprio(0)}; counted vmcnt(6)
// once per tile (never 0 mid-loop). No big register arrays (R7 spill lesson).
template<bool OUT_F32>
__device__ __forceinline__ void gemm_body(bf16_t* S,
                                          const bf16_t* __restrict__ A,
                                          const bf16_t* __restrict__ W,
                                          const float* __restrict__ bias,
                                          void* __restrict__ Cout,
                                          int M, int N, int K, int bx, int by) {
  const int tid = threadIdx.x;           // 0..511
  const int l = tid & 63, w = tid >> 6;  // 8 waves
  const int wr = w >> 1, wc = w & 1;     // 4M x 2N
  const int g = l >> 4, r = l & 15;
  const int m0 = by * 256, n0 = bx * 128;
  const int wbase = w * 512;             // wave-uniform LDS base (elements)

  auto stageA2 = [&](int q, int t, int half) {  // 2 of A's 4 GLLs
#pragma unroll
    for (int it = half * 2; it < half * 2 + 2; ++it) {
      int idx = it * 512 + tid;
      int row = idx >> 3, c = (idx & 7) ^ (row & 7);
      GLL16(A + (size_t)(m0 + row) * K + (t << 6) + c * 8,
            S + q * 24576 + it * 4096 + wbase);
    }
  };
  auto stageB2 = [&](int q, int t) {            // B's 2 GLLs
#pragma unroll
    for (int it = 0; it < 2; ++it) {
      int idx = it * 512 + tid;
      int row = idx >> 3, c = (idx & 7) ^ (row & 7);
      GLL16(W + (size_t)(n0 + row) * K + (t << 6) + c * 8,
            S + q * 24576 + 16384 + it * 4096 + wbase);
    }
  };

  f32x4 acc[4][4] = {};
  const int NKT = K >> 6;

  // prologue: tiles 0,1 fully staged (12 GLLs in flight)
  stageA2(0, 0, 0); stageA2(0, 0, 1); stageB2(0, 0);
  stageA2(1, 1, 0); stageA2(1, 1, 1); stageB2(1, 1);

  int q = 0;
  for (int t = 0; t < NKT; ++t) {
    const bool pf = (t + 2 < NKT);
    int q2 = q + 2; if (q2 >= 3) q2 -= 3;

    // counted vmcnt: in-flight = t(6), t+1(6); retire exactly tile t's
    if (t + 1 < NKT) asm volatile("s_waitcnt vmcnt(6)" ::: "memory");
    else             asm volatile("s_waitcnt vmcnt(0)" ::: "memory");
    __builtin_amdgcn_s_barrier();        // tile t visible to all waves

    const bf16_t* a_ = S + q * 24576;
    const bf16_t* b_ = a_ + 16384;

#pragma unroll
    for (int kk = 0; kk < 2; ++kk) {
      bf16x8 bw[4];
#pragma unroll
      for (int n = 0; n < 4; ++n) {      // B frags for this kk (phase 0/2 reads)
        int row = wc * 64 + n * 16 + r;
        bw[n] = *(const bf16x8*)(b_ + row * 64 + (((kk * 4 + g) ^ (row & 7)) << 3));
      }
#pragma unroll
      for (int mh = 0; mh < 2; ++mh) {   // phase = (kk, mh): 8 MFMA each
        bf16x8 af[2];
#pragma unroll
        for (int i = 0; i < 2; ++i) {
          int row = wr * 64 + (mh * 2 + i) * 16 + r;
          af[i] = *(const bf16x8*)(a_ + row * 64 + (((kk * 4 + g) ^ (row & 7)) << 3));
        }
        if (pf) {                        // spread tile t+2's 6 GLLs over phases
          int ph = kk * 2 + mh;
          if (ph == 0)      stageA2(q2, t + 2, 0);
          else if (ph == 1) stageA2(q2, t + 2, 1);
          else if (ph == 2) stageB2(q2, t + 2);
        }
        __builtin_amdgcn_s_barrier();    // pacing barrier (no vmcnt drain)
        asm volatile("s_waitcnt lgkmcnt(0)" ::: "memory");
        __builtin_amdgcn_sched_barrier(0);  // rule 18: fence MFMA hoist
        __builtin_amdgcn_s_setprio(1);
#pragma unroll
        for (int i = 0; i < 2; ++i)
#pragma unroll
          for (int n = 0; n < 4; ++n)
            acc[mh * 2 + i][n] = __builtin_amdgcn_mfma_f32_16x16x32_bf16(
                af[i], bw[n], acc[mh * 2 + i][n], 0, 0, 0);
        __builtin_amdgcn_s_setprio(0);
        __builtin_amdgcn_sched_barrier(0);
      }
    }
    ++q; if (q >= 3) q -= 3;
  }

#pragma unroll
  for (int n = 0; n < 4; ++n) {
    int col = n0 + wc * 64 + n * 16 + r;
    float bv = bias[col];
#pragma unroll
    for (int m = 0; m < 4; ++m) {
      int row0 = m0 + wr * 64 + m * 16 + g * 4;
#pragma unroll
      for (int j = 0; j < 4; ++j) {
        float vv = acc[m][n][j] + bv;
        if (OUT_F32)
          ((float*)Cout)[(size_t)(row0 + j) * N + col] = vv;
        else
          ((bf16_t*)Cout)[(size_t)(row0 + j) * N + col] = (bf16_t)vv;
      }
    }
  }
}

// O-projection: grid 256 = exactly 1 round at 1 block/CU; XCD-grouped.
__global__ __launch_bounds__(512, 2) void gemm_bt(const bf16_t* __restrict__ A,
                                                  const bf16_t* __restrict__ W,
                                                  const float* __restrict__ bias,
                                                  float* __restrict__ Cout,
                                                  int M, int N, int K) {
  __shared__ bf16_t S[3 * 24576];
  const int o = blockIdx.x;
  const int xcd = o & 7, s = o >> 3;   // s in [0,32)
  const int bx = s & 7, u = s >> 3;    // u in [0,4)
  const int by = xcd + 8 * u;          // all bx of one by share an XCD
  gemm_body<true>(S, A, W, bias, (void*)Cout, M, N, K, bx, by);
}

// QKV: grid 768 = exactly 3 rounds at 1 block/CU; XCD-grouped.
__global__ __launch_bounds__(512, 2) void gemm_qkv(
    const bf16_t* A0, const bf16_t* W0, const float* b0, bf16_t* C0,
    const bf16_t* A1, const bf16_t* W1, const float* b1, bf16_t* C1,
    const bf16_t* A2, const bf16_t* W2, const float* b2, bf16_t* C2,
    int M, int N, int K) {
  __shared__ bf16_t S[3 * 24576];
  const int o = blockIdx.x;
  const int xcd = o & 7, s = o >> 3;   // s in [0,96)
  const int bx = s & 7, u = s >> 3;    // u in [0,12)
  const int zby = xcd + 8 * u;         // 0..95
  const int z = zby >> 5, by = zby & 31;
  const bf16_t* A = z == 0 ? A0 : z == 1 ? A1 : A2;
  const bf16_t* W = z == 0 ? W0 : z == 1 ? W1 : W2;
  const float* bb = z == 0 ? b0 : z == 1 ? b1 : b2;
  bf16_t* C = z == 0 ? C0 : z == 1 ? C1 : C2;
  gemm_body<false>(S, A, W, bb, (void*)C, M, N, K, bx, by);
}

// ---------------- causal flash attention (2-phase, swapped QK^T) ----------
// (unchanged from R5 — proven ~50 µs)
__global__ __launch_bounds__(256, 4) void attn_kernel(const bf16_t* __restrict__ Q1,
                                                      const bf16_t* __restrict__ K1,
                                                      const bf16_t* __restrict__ V1,
                                                      bf16_t* __restrict__ attn) {
  __shared__ bf16_t Kt[2][64 * 64];
  __shared__ bf16_t Vt[2][64 * 64];
  __shared__ bf16_t Pl[4][16 * 64];

  const int tid = threadIdx.x;
  const int l = tid & 63, w = tid >> 6;
  const int g = l >> 4, r = l & 15;

  const int o = blockIdx.x;
  const int os = (o & 7) * 128 + (o >> 3);
  const int pair = os & 7, hb = os >> 3;
  const int h = hb & 15, b = hb >> 4;

  constexpr float SC = 0.18033688011112042f;  // 0.125 * log2(e)

  for (int ph = 0; ph < 2; ++ph) {
    const int qt = ph ? (NT - 1 - pair) : pair;
    const int qrow_g = qt * 64 + w * 16 + r;

    const bf16_t* qptr = Q1 + ((size_t)b * NS + qrow_g) * ND + h * 64;
    bf16x8 qf0 = *(const bf16x8*)(qptr + g * 8);
    bf16x8 qf1 = *(const bf16x8*)(qptr + 32 + g * 8);
#pragma unroll
    for (int i = 0; i < 8; ++i) {
      qf0[i] = (bf16_t)((float)qf0[i] * SC);
      qf1[i] = (bf16_t)((float)qf1[i] * SC);
    }

    float mrun = -1e30f, lrun = 0.f;
    f32x4 oacc[4] = {};

    __syncthreads();

    bf16x8 vr0, vr1;
    {
#pragma unroll
      for (int it = 0; it < 2; ++it) {
        int idx = it * 256 + tid;
        int key = idx >> 3;
        int dkg = ((idx & 7) ^ (key & 7)) << 3;
        GLL16(K1 + ((size_t)b * NS + key) * ND + h * 64 + dkg,
              &Kt[0][(it * 256 + w * 64) * 8]);
      }
      vr0 = *(const bf16x8*)(V1 + ((size_t)b * NS + l) * ND + h * 64 + w * 8);
      vr1 = *(const bf16x8*)(V1 + ((size_t)b * NS + l) * ND + h * 64 + (4 + w) * 8);
    }

    for (int kt = 0; kt <= qt; ++kt) {
      const int p = kt & 1;
      const int k0 = kt * 64;

#pragma unroll
      for (int it = 0; it < 2; ++it) {
        int dkb = (it * 4 + w) * 8;
#pragma unroll
        for (int jj = 0; jj < 8; ++jj) {
          int dk = dkb + jj;
          int boff = dk * 128 + ((l * 2) ^ ((dk & 7) << 4));
          *(bf16_t*)((char*)Vt[p] + boff) = (it ? vr1 : vr0)[jj];
        }
      }
      __syncthreads();

      if (kt < qt) {
        const int k0n = k0 + 64;
#pragma unroll
        for (int it = 0; it < 2; ++it) {
          int idx = it * 256 + tid;
          int key = idx >> 3;
          int dkg = ((idx & 7) ^ (key & 7)) << 3;
          GLL16(K1 + ((size_t)b * NS + k0n + key) * ND + h * 64 + dkg,
                &Kt[p ^ 1][(it * 256 + w * 64) * 8]);
        }
        vr0 = *(const bf16x8*)(V1 + ((size_t)b * NS + k0n + l) * ND + h * 64 + w * 8);
        vr1 = *(const bf16x8*)(V1 + ((size_t)b * NS + k0n + l) * ND + h * 64 + (4 + w) * 8);
      }

      f32x4 sacc[4] = {};
      __builtin_amdgcn_s_setprio(1);
#pragma unroll
      for (int n = 0; n < 4; ++n) {
        int key = n * 16 + r;
#pragma unroll
        for (int kk = 0; kk < 2; ++kk) {
          int dk2 = kk * 32 + g * 8;
          int boff = key * 128 + ((dk2 * 2) ^ ((key & 7) << 4));
          bf16x8 kf = *(const bf16x8*)((char*)Kt[p] + boff);
          sacc[n] = __builtin_amdgcn_mfma_f32_16x16x32_bf16(kf, kk == 0 ? qf0 : qf1, sacc[n], 0, 0, 0);
        }
      }
      __builtin_amdgcn_s_setprio(0);

      if (kt == qt) {
#pragma unroll
        for (int n = 0; n < 4; ++n)
#pragma unroll
          for (int j = 0; j < 4; ++j)
            if (k0 + n * 16 + g * 4 + j > qrow_g) sacc[n][j] = -1e30f;
      }

      float mx;
      {
        float t0 = fmaxf(fmaxf(sacc[0][0], sacc[0][1]), fmaxf(sacc[0][2], sacc[0][3]));
        float t1 = fmaxf(fmaxf(sacc[1][0], sacc[1][1]), fmaxf(sacc[1][2], sacc[1][3]));
        float t2 = fmaxf(fmaxf(sacc[2][0], sacc[2][1]), fmaxf(sacc[2][2], sacc[2][3]));
        float t3 = fmaxf(fmaxf(sacc[3][0], sacc[3][1]), fmaxf(sacc[3][2], sacc[3][3]));
        mx = fmaxf(fmaxf(t0, t1), fmaxf(t2, t3));
      }
      mx = fmaxf(mx, __shfl_xor(mx, 16));
      mx = fmaxf(mx, __shfl_xor(mx, 32));

      if (!__all(mx <= mrun + 8.0f)) {
        float m_new = fmaxf(mrun, mx);
        float esc = __builtin_amdgcn_exp2f(mrun - m_new);
        mrun = m_new;
        lrun *= esc;
#pragma unroll
        for (int n = 0; n < 4; ++n)
#pragma unroll
          for (int j = 0; j < 4; ++j) oacc[n][j] *= esc;
      }

      float rsum = 0.f;
#pragma unroll
      for (int n = 0; n < 4; ++n) {
        bf16x4 p4;
#pragma unroll
        for (int j = 0; j < 4; ++j) {
          float pe = __builtin_amdgcn_exp2f(sacc[n][j] - mrun);
          rsum += pe;
          p4[j] = (bf16_t)pe;
        }
        *(bf16x4*)((char*)Pl[w] + r * 128 + ((n * 32 + g * 8) ^ ((r & 7) << 4))) = p4;
      }
      rsum += __shfl_xor(rsum, 16);
      rsum += __shfl_xor(rsum, 32);
      lrun += rsum;

      __builtin_amdgcn_s_setprio(1);
#pragma unroll
      for (int kk = 0; kk < 2; ++kk) {
        bf16x8 pf = *(const bf16x8*)((char*)Pl[w] + r * 128 + ((kk * 64 + g * 16) ^ ((r & 7) << 4)));
#pragma unroll
        for (int n = 0; n < 4; ++n) {
          int dkr = n * 16 + r;
          bf16x8 vf = *(const bf16x8*)((char*)Vt[p] + dkr * 128 + ((kk * 64 + g * 16) ^ ((r & 7) << 4)));
          oacc[n] = __builtin_amdgcn_mfma_f32_16x16x32_bf16(vf, pf, oacc[n], 0, 0, 0);
        }
      }
      __builtin_amdgcn_s_setprio(0);
    }  // kt

    float linv = 1.0f / lrun;
#pragma unroll
    for (int n = 0; n < 4; ++n) {
      bf16x4 o4;
#pragma unroll
      for (int j = 0; j < 4; ++j) o4[j] = (bf16_t)(oacc[n][j] * linv);
      *(bf16x4*)(attn + ((size_t)b * NS + qrow_g) * ND + h * 64 + n * 16 + g * 4) = o4;
    }
  }  // ph
}

// ---------------- launch ----------------
extern "C" void kernel_launch(void* const* d_in, const int* in_sizes, int n_in,
                              void* d_out, int out_size, void* d_ws, size_t ws_size,
                              hipStream_t stream) {
  const float* q  = (const float*)d_in[0];
  const float* k  = (const float*)d_in[1];
  const float* v  = (const float*)d_in[2];
  // d_in[3] = mask (int32 tril, implemented analytically)
  const float* Wq = (const float*)d_in[4];
  const float* bq = (const float*)d_in[5];
  const float* Wk = (const float*)d_in[6];
  const float* bk = (const float*)d_in[7];
  const float* Wv = (const float*)d_in[8];
  const float* bv = (const float*)d_in[9];
  const float* Wo = (const float*)d_in[10];
  const float* bo = (const float*)d_in[11];
  float* out = (float*)d_out;

  const size_t NX = (size_t)NB * NS * ND;  // 8388608
  const size_t NW = (size_t)ND * ND;       // 1048576
  char* ws = (char*)d_ws;
  size_t off = 0;
  auto alloc = [&](size_t bytes) {
    char* p = ws + off;
    off += (bytes + 255) & ~(size_t)255;
    return p;
  };
  bf16_t* xq  = (bf16_t*)alloc(NX * 2);
  bf16_t* xk  = (bf16_t*)alloc(NX * 2);
  bf16_t* xv  = (bf16_t*)alloc(NX * 2);
  bf16_t* wqb = (bf16_t*)alloc(NW * 2);
  bf16_t* wkb = (bf16_t*)alloc(NW * 2);
  bf16_t* wvb = (bf16_t*)alloc(NW * 2);
  bf16_t* wob = (bf16_t*)alloc(NW * 2);
  bf16_t* q1  = (bf16_t*)alloc(NX * 2);
  bf16_t* k1  = (bf16_t*)alloc(NX * 2);
  bf16_t* v1  = (bf16_t*)alloc(NX * 2);
  bf16_t* at  = xq;  // xq dead after QKV GEMMs; reuse for attn output

  dim3 blk(256);
  cvt3_kernel<<<dim3(1024, 3), blk, 0, stream>>>(q, xq, k, xk, v, xv, (long)NX);
  cvt4_kernel<<<dim3(128, 4), blk, 0, stream>>>(Wq, wqb, Wk, wkb, Wv, wvb, Wo, wob, (long)NW);

  gemm_qkv<<<dim3(768), dim3(512), 0, stream>>>(
      xq, wqb, bq, q1, xk, wkb, bk, k1, xv, wvb, bv, v1, NB * NS, ND, ND);

  attn_kernel<<<dim3((NT / 2) * NH * NB), blk, 0, stream>>>(q1, k1, v1, at);

  gemm_bt<<<dim3(256), dim3(512), 0, stream>>>(at, wob, bo, out, NB * NS, ND, ND);
}

// Round 9
// 148.362 us; speedup vs baseline: 2.2204x; 1.0668x over previous
//
#include <hip/hip_runtime.h>
#include <hip/hip_bf16.h>
#include <stdint.h>

// Problem constants
constexpr int NB = 8;     // batch
constexpr int NS = 1024;  // seq
constexpr int ND = 1024;  // model dim
constexpr int NH = 16;    // heads
constexpr int NDK = 64;   // head dim
constexpr int NT = NS / 64;   // 16 q-tiles of 64 rows
constexpr int NKT = ND / 64;  // 16 K-tiles per GEMM

typedef __bf16 bf16_t;
typedef __attribute__((ext_vector_type(8))) __bf16 bf16x8;
typedef __attribute__((ext_vector_type(4))) __bf16 bf16x4;
typedef __attribute__((ext_vector_type(4))) float f32x4;

#define GLL16(g, s) __builtin_amdgcn_global_load_lds( \
    (const __attribute__((address_space(1))) void*)(g), \
    (__attribute__((address_space(3))) void*)(s), 16, 0, 0)

// ---------------- fp32 -> bf16 convert (weights only now) ----------------
__device__ __forceinline__ void cvt_body(const float* __restrict__ s,
                                         bf16_t* __restrict__ d, long n) {
  long i0 = (long)(blockIdx.x * blockDim.x + threadIdx.x) * 4;
  long step = (long)gridDim.x * blockDim.x * 4;
  for (long i = i0; i < n; i += step) {
    float4 f = *(const float4*)(s + i);
    bf16x4 o;
    o[0] = (bf16_t)f.x; o[1] = (bf16_t)f.y; o[2] = (bf16_t)f.z; o[3] = (bf16_t)f.w;
    *(bf16x4*)(d + i) = o;
  }
}

__global__ __launch_bounds__(256) void cvt4_kernel(const float* s0, bf16_t* d0,
                                                   const float* s1, bf16_t* d1,
                                                   const float* s2, bf16_t* d2,
                                                   const float* s3, bf16_t* d3, long n) {
  const float* s = blockIdx.y == 0 ? s0 : blockIdx.y == 1 ? s1 : blockIdx.y == 2 ? s2 : s3;
  bf16_t* d = blockIdx.y == 0 ? d0 : blockIdx.y == 1 ? d1 : blockIdx.y == 2 ? d2 : d3;
  cvt_body(s, d, n);
}

// ---------------- QKV GEMM with FUSED fp32->bf16 A-convert ----------------
// C[M,128] = A_f32[M,K] @ W_bf16[N,K]^T + bias. 256x128 tile, 8 waves
// (4M x 2N, per-wave 64x64), BK=64. A: reg-staged {8x global_load_dwordx4
// fp32 issued early -> cvt -> swizzled ds_write_b128 late} (T14) into 2 LDS
// bufs (32KB ea). B: GLL16 XOR-swizzled (proven 0-conflict) into 3 bufs
// (16KB ea). 112KB LDS, 1 block/CU. One barrier per K-tile. Counted ledger:
// body(t): issue A(t+1):8, B(t+2):2 -> compute(t) -> vmcnt(2) [retire
// A(t+1)+B(t+1), keep B(t+2)] -> sched_barrier -> writeA(t+1) -> lgkm+bar.
__global__ __launch_bounds__(512, 2) void gemm_qkv(
    const float* A0, const bf16_t* W0, const float* b0, bf16_t* C0,
    const float* A1, const bf16_t* W1, const float* b1, bf16_t* C1,
    const float* A2, const bf16_t* W2, const float* b2, bf16_t* C2) {
  __shared__ bf16_t S[2 * 16384 + 3 * 8192];  // A 64KB + B 48KB
  const int o = blockIdx.x;
  const int xcd = o & 7, s = o >> 3;   // s in [0,96)
  const int bx = s & 7, u = s >> 3;    // u in [0,12)
  const int zby = xcd + 8 * u;         // 0..95
  const int z = zby >> 5, by = zby & 31;
  const float* A = z == 0 ? A0 : z == 1 ? A1 : A2;
  const bf16_t* W = z == 0 ? W0 : z == 1 ? W1 : W2;
  const float* bb = z == 0 ? b0 : z == 1 ? b1 : b2;
  bf16_t* C = z == 0 ? C0 : z == 1 ? C1 : C2;

  const int tid = threadIdx.x;           // 0..511
  const int l = tid & 63, w = tid >> 6;  // 8 waves
  const int wr = w >> 1, wc = w & 1;     // 4M x 2N
  const int g = l >> 4, r = l & 15;
  const int m0 = by * 256, n0 = bx * 128;
  const int wbase = w * 512;

  bf16_t* Ab = S;           // 2 x 16384 elems
  bf16_t* Bb = S + 32768;   // 3 x 8192 elems

  float4 fa[8];
  auto issueA = [&](int t) {
#pragma unroll
    for (int it = 0; it < 4; ++it) {
      const float* p = A + (size_t)(m0 + it * 64 + (tid >> 3)) * ND + t * 64 + (tid & 7) * 8;
      fa[it * 2]     = *(const float4*)p;
      fa[it * 2 + 1] = *(const float4*)(p + 4);
    }
  };
  auto writeA = [&](int ab) {
#pragma unroll
    for (int it = 0; it < 4; ++it) {
      int row = it * 64 + (tid >> 3), c = tid & 7;
      bf16x8 ov;
      ov[0] = (bf16_t)fa[it * 2].x;     ov[1] = (bf16_t)fa[it * 2].y;
      ov[2] = (bf16_t)fa[it * 2].z;     ov[3] = (bf16_t)fa[it * 2].w;
      ov[4] = (bf16_t)fa[it * 2 + 1].x; ov[5] = (bf16_t)fa[it * 2 + 1].y;
      ov[6] = (bf16_t)fa[it * 2 + 1].z; ov[7] = (bf16_t)fa[it * 2 + 1].w;
      *(bf16x8*)(Ab + ab * 16384 + row * 64 + ((c ^ (row & 7)) << 3)) = ov;
    }
  };
  auto stageB = [&](int qb, int t) {
#pragma unroll
    for (int it = 0; it < 2; ++it) {
      int idx = it * 512 + tid;
      int row = idx >> 3, c = (idx & 7) ^ (row & 7);
      GLL16(W + (size_t)(n0 + row) * ND + (t << 6) + c * 8,
            Bb + qb * 8192 + it * 4096 + wbase);
    }
  };

  f32x4 acc[4][4] = {};

  // prologue: A(0):8, B(0):2, B(1):2 -> drain -> write A(0) -> publish
  issueA(0);
  stageB(0, 0);
  stageB(1, 1);
  asm volatile("s_waitcnt vmcnt(0)" ::: "memory");
  __builtin_amdgcn_sched_barrier(0);
  writeA(0);
  asm volatile("s_waitcnt lgkmcnt(0)" ::: "memory");
  __builtin_amdgcn_s_barrier();

  for (int t = 0; t < NKT; ++t) {
    if (t + 1 < NKT) issueA(t + 1);
    __builtin_amdgcn_sched_barrier(0);   // pin: A issues before B issues
    if (t + 2 < NKT) stageB((t + 2) % 3, t + 2);
    __builtin_amdgcn_sched_barrier(0);   // pin: issues before compute

    const bf16_t* a_ = Ab + (t & 1) * 16384;
    const bf16_t* b_ = Bb + (t % 3) * 8192;
#pragma unroll
    for (int kk = 0; kk < 2; ++kk) {
      bf16x8 af[4], bw[4];
#pragma unroll
      for (int m = 0; m < 4; ++m) {
        int row = wr * 64 + m * 16 + r;
        af[m] = *(const bf16x8*)(a_ + row * 64 + (((kk * 4 + g) ^ (row & 7)) << 3));
      }
#pragma unroll
      for (int n = 0; n < 4; ++n) {
        int row = wc * 64 + n * 16 + r;
        bw[n] = *(const bf16x8*)(b_ + row * 64 + (((kk * 4 + g) ^ (row & 7)) << 3));
      }
      __builtin_amdgcn_s_setprio(1);
#pragma unroll
      for (int m = 0; m < 4; ++m)
#pragma unroll
        for (int n = 0; n < 4; ++n)
          acc[m][n] = __builtin_amdgcn_mfma_f32_16x16x32_bf16(af[m], bw[n], acc[m][n], 0, 0, 0);
      __builtin_amdgcn_s_setprio(0);
    }

    if (t + 1 < NKT) {
      // retire A(t+1) [+B(t+1)]; keep B(t+2) in flight (never drain mid-loop)
      if (t + 2 < NKT) asm volatile("s_waitcnt vmcnt(2)" ::: "memory");
      else             asm volatile("s_waitcnt vmcnt(0)" ::: "memory");
      __builtin_amdgcn_sched_barrier(0); // rule 18: fa used below
      writeA((t + 1) & 1);
    }
    asm volatile("s_waitcnt lgkmcnt(0)" ::: "memory");
    __builtin_amdgcn_s_barrier();        // publish tile t+1
  }

#pragma unroll
  for (int n = 0; n < 4; ++n) {
    int col = n0 + wc * 64 + n * 16 + r;
    float bv = bb[col];
#pragma unroll
    for (int m = 0; m < 4; ++m) {
      int row0 = m0 + wr * 64 + m * 16 + g * 4;
#pragma unroll
      for (int j = 0; j < 4; ++j)
        C[(size_t)(row0 + j) * ND + col] = (bf16_t)(acc[m][n][j] + bv);
    }
  }
}

// ---------------- O-projection GEMM (unchanged R8 structure) ----------------
// 256x128 tile, 8 waves 4Mx2N, BK=64, triple-buffered GLL16 LDS, counted
// vmcnt, fine phases. bf16 A (attn output), fp32 C out.
__global__ __launch_bounds__(512, 2) void gemm_bt(const bf16_t* __restrict__ A,
                                                  const bf16_t* __restrict__ W,
                                                  const float* __restrict__ bias,
                                                  float* __restrict__ Cout,
                                                  int M, int N, int K) {
  __shared__ bf16_t S[3 * 24576];
  const int o = blockIdx.x;
  const int xcd = o & 7, s = o >> 3;   // s in [0,32)
  const int bx = s & 7, u = s >> 3;    // u in [0,4)
  const int by = xcd + 8 * u;

  const int tid = threadIdx.x;
  const int l = tid & 63, w = tid >> 6;
  const int wr = w >> 1, wc = w & 1;
  const int g = l >> 4, r = l & 15;
  const int m0 = by * 256, n0 = bx * 128;
  const int wbase = w * 512;

  auto stageA2 = [&](int q, int t, int half) {
#pragma unroll
    for (int it = half * 2; it < half * 2 + 2; ++it) {
      int idx = it * 512 + tid;
      int row = idx >> 3, c = (idx & 7) ^ (row & 7);
      GLL16(A + (size_t)(m0 + row) * K + (t << 6) + c * 8,
            S + q * 24576 + it * 4096 + wbase);
    }
  };
  auto stageB2 = [&](int q, int t) {
#pragma unroll
    for (int it = 0; it < 2; ++it) {
      int idx = it * 512 + tid;
      int row = idx >> 3, c = (idx & 7) ^ (row & 7);
      GLL16(W + (size_t)(n0 + row) * K + (t << 6) + c * 8,
            S + q * 24576 + 16384 + it * 4096 + wbase);
    }
  };

  f32x4 acc[4][4] = {};
  const int NKT2 = K >> 6;

  stageA2(0, 0, 0); stageA2(0, 0, 1); stageB2(0, 0);
  stageA2(1, 1, 0); stageA2(1, 1, 1); stageB2(1, 1);

  int q = 0;
  for (int t = 0; t < NKT2; ++t) {
    const bool pf = (t + 2 < NKT2);
    int q2 = q + 2; if (q2 >= 3) q2 -= 3;

    if (t + 1 < NKT2) asm volatile("s_waitcnt vmcnt(6)" ::: "memory");
    else              asm volatile("s_waitcnt vmcnt(0)" ::: "memory");
    __builtin_amdgcn_s_barrier();

    const bf16_t* a_ = S + q * 24576;
    const bf16_t* b_ = a_ + 16384;

#pragma unroll
    for (int kk = 0; kk < 2; ++kk) {
      bf16x8 bw[4];
#pragma unroll
      for (int n = 0; n < 4; ++n) {
        int row = wc * 64 + n * 16 + r;
        bw[n] = *(const bf16x8*)(b_ + row * 64 + (((kk * 4 + g) ^ (row & 7)) << 3));
      }
#pragma unroll
      for (int mh = 0; mh < 2; ++mh) {
        bf16x8 af[2];
#pragma unroll
        for (int i = 0; i < 2; ++i) {
          int row = wr * 64 + (mh * 2 + i) * 16 + r;
          af[i] = *(const bf16x8*)(a_ + row * 64 + (((kk * 4 + g) ^ (row & 7)) << 3));
        }
        if (pf) {
          int ph = kk * 2 + mh;
          if (ph == 0)      stageA2(q2, t + 2, 0);
          else if (ph == 1) stageA2(q2, t + 2, 1);
          else if (ph == 2) stageB2(q2, t + 2);
        }
        __builtin_amdgcn_s_barrier();
        asm volatile("s_waitcnt lgkmcnt(0)" ::: "memory");
        __builtin_amdgcn_sched_barrier(0);
        __builtin_amdgcn_s_setprio(1);
#pragma unroll
        for (int i = 0; i < 2; ++i)
#pragma unroll
          for (int n = 0; n < 4; ++n)
            acc[mh * 2 + i][n] = __builtin_amdgcn_mfma_f32_16x16x32_bf16(
                af[i], bw[n], acc[mh * 2 + i][n], 0, 0, 0);
        __builtin_amdgcn_s_setprio(0);
        __builtin_amdgcn_sched_barrier(0);
      }
    }
    ++q; if (q >= 3) q -= 3;
  }

#pragma unroll
  for (int n = 0; n < 4; ++n) {
    int col = n0 + wc * 64 + n * 16 + r;
    float bv = bias[col];
#pragma unroll
    for (int m = 0; m < 4; ++m) {
      int row0 = m0 + wr * 64 + m * 16 + g * 4;
#pragma unroll
      for (int j = 0; j < 4; ++j)
        Cout[(size_t)(row0 + j) * N + col] = acc[m][n][j] + bv;
    }
  }
}

// ---------------- causal flash attention (2-phase, swapped QK^T) ----------
// (unchanged from R5 — proven ~50 µs)
__global__ __launch_bounds__(256, 4) void attn_kernel(const bf16_t* __restrict__ Q1,
                                                      const bf16_t* __restrict__ K1,
                                                      const bf16_t* __restrict__ V1,
                                                      bf16_t* __restrict__ attn) {
  __shared__ bf16_t Kt[2][64 * 64];
  __shared__ bf16_t Vt[2][64 * 64];
  __shared__ bf16_t Pl[4][16 * 64];

  const int tid = threadIdx.x;
  const int l = tid & 63, w = tid >> 6;
  const int g = l >> 4, r = l & 15;

  const int o = blockIdx.x;
  const int os = (o & 7) * 128 + (o >> 3);
  const int pair = os & 7, hb = os >> 3;
  const int h = hb & 15, b = hb >> 4;

  constexpr float SC = 0.18033688011112042f;  // 0.125 * log2(e)

  for (int ph = 0; ph < 2; ++ph) {
    const int qt = ph ? (NT - 1 - pair) : pair;
    const int qrow_g = qt * 64 + w * 16 + r;

    const bf16_t* qptr = Q1 + ((size_t)b * NS + qrow_g) * ND + h * 64;
    bf16x8 qf0 = *(const bf16x8*)(qptr + g * 8);
    bf16x8 qf1 = *(const bf16x8*)(qptr + 32 + g * 8);
#pragma unroll
    for (int i = 0; i < 8; ++i) {
      qf0[i] = (bf16_t)((float)qf0[i] * SC);
      qf1[i] = (bf16_t)((float)qf1[i] * SC);
    }

    float mrun = -1e30f, lrun = 0.f;
    f32x4 oacc[4] = {};

    __syncthreads();

    bf16x8 vr0, vr1;
    {
#pragma unroll
      for (int it = 0; it < 2; ++it) {
        int idx = it * 256 + tid;
        int key = idx >> 3;
        int dkg = ((idx & 7) ^ (key & 7)) << 3;
        GLL16(K1 + ((size_t)b * NS + key) * ND + h * 64 + dkg,
              &Kt[0][(it * 256 + w * 64) * 8]);
      }
      vr0 = *(const bf16x8*)(V1 + ((size_t)b * NS + l) * ND + h * 64 + w * 8);
      vr1 = *(const bf16x8*)(V1 + ((size_t)b * NS + l) * ND + h * 64 + (4 + w) * 8);
    }

    for (int kt = 0; kt <= qt; ++kt) {
      const int p = kt & 1;
      const int k0 = kt * 64;

#pragma unroll
      for (int it = 0; it < 2; ++it) {
        int dkb = (it * 4 + w) * 8;
#pragma unroll
        for (int jj = 0; jj < 8; ++jj) {
          int dk = dkb + jj;
          int boff = dk * 128 + ((l * 2) ^ ((dk & 7) << 4));
          *(bf16_t*)((char*)Vt[p] + boff) = (it ? vr1 : vr0)[jj];
        }
      }
      __syncthreads();

      if (kt < qt) {
        const int k0n = k0 + 64;
#pragma unroll
        for (int it = 0; it < 2; ++it) {
          int idx = it * 256 + tid;
          int key = idx >> 3;
          int dkg = ((idx & 7) ^ (key & 7)) << 3;
          GLL16(K1 + ((size_t)b * NS + k0n + key) * ND + h * 64 + dkg,
                &Kt[p ^ 1][(it * 256 + w * 64) * 8]);
        }
        vr0 = *(const bf16x8*)(V1 + ((size_t)b * NS + k0n + l) * ND + h * 64 + w * 8);
        vr1 = *(const bf16x8*)(V1 + ((size_t)b * NS + k0n + l) * ND + h * 64 + (4 + w) * 8);
      }

      f32x4 sacc[4] = {};
      __builtin_amdgcn_s_setprio(1);
#pragma unroll
      for (int n = 0; n < 4; ++n) {
        int key = n * 16 + r;
#pragma unroll
        for (int kk = 0; kk < 2; ++kk) {
          int dk2 = kk * 32 + g * 8;
          int boff = key * 128 + ((dk2 * 2) ^ ((key & 7) << 4));
          bf16x8 kf = *(const bf16x8*)((char*)Kt[p] + boff);
          sacc[n] = __builtin_amdgcn_mfma_f32_16x16x32_bf16(kf, kk == 0 ? qf0 : qf1, sacc[n], 0, 0, 0);
        }
      }
      __builtin_amdgcn_s_setprio(0);

      if (kt == qt) {
#pragma unroll
        for (int n = 0; n < 4; ++n)
#pragma unroll
          for (int j = 0; j < 4; ++j)
            if (k0 + n * 16 + g * 4 + j > qrow_g) sacc[n][j] = -1e30f;
      }

      float mx;
      {
        float t0 = fmaxf(fmaxf(sacc[0][0], sacc[0][1]), fmaxf(sacc[0][2], sacc[0][3]));
        float t1 = fmaxf(fmaxf(sacc[1][0], sacc[1][1]), fmaxf(sacc[1][2], sacc[1][3]));
        float t2 = fmaxf(fmaxf(sacc[2][0], sacc[2][1]), fmaxf(sacc[2][2], sacc[2][3]));
        float t3 = fmaxf(fmaxf(sacc[3][0], sacc[3][1]), fmaxf(sacc[3][2], sacc[3][3]));
        mx = fmaxf(fmaxf(t0, t1), fmaxf(t2, t3));
      }
      mx = fmaxf(mx, __shfl_xor(mx, 16));
      mx = fmaxf(mx, __shfl_xor(mx, 32));

      if (!__all(mx <= mrun + 8.0f)) {
        float m_new = fmaxf(mrun, mx);
        float esc = __builtin_amdgcn_exp2f(mrun - m_new);
        mrun = m_new;
        lrun *= esc;
#pragma unroll
        for (int n = 0; n < 4; ++n)
#pragma unroll
          for (int j = 0; j < 4; ++j) oacc[n][j] *= esc;
      }

      float rsum = 0.f;
#pragma unroll
      for (int n = 0; n < 4; ++n) {
        bf16x4 p4;
#pragma unroll
        for (int j = 0; j < 4; ++j) {
          float pe = __builtin_amdgcn_exp2f(sacc[n][j] - mrun);
          rsum += pe;
          p4[j] = (bf16_t)pe;
        }
        *(bf16x4*)((char*)Pl[w] + r * 128 + ((n * 32 + g * 8) ^ ((r & 7) << 4))) = p4;
      }
      rsum += __shfl_xor(rsum, 16);
      rsum += __shfl_xor(rsum, 32);
      lrun += rsum;

      __builtin_amdgcn_s_setprio(1);
#pragma unroll
      for (int kk = 0; kk < 2; ++kk) {
        bf16x8 pf = *(const bf16x8*)((char*)Pl[w] + r * 128 + ((kk * 64 + g * 16) ^ ((r & 7) << 4)));
#pragma unroll
        for (int n = 0; n < 4; ++n) {
          int dkr = n * 16 + r;
          bf16x8 vf = *(const bf16x8*)((char*)Vt[p] + dkr * 128 + ((kk * 64 + g * 16) ^ ((r & 7) << 4)));
          oacc[n] = __builtin_amdgcn_mfma_f32_16x16x32_bf16(vf, pf, oacc[n], 0, 0, 0);
        }
      }
      __builtin_amdgcn_s_setprio(0);
    }  // kt

    float linv = 1.0f / lrun;
#pragma unroll
    for (int n = 0; n < 4; ++n) {
      bf16x4 o4;
#pragma unroll
      for (int j = 0; j < 4; ++j) o4[j] = (bf16_t)(oacc[n][j] * linv);
      *(bf16x4*)(attn + ((size_t)b * NS + qrow_g) * ND + h * 64 + n * 16 + g * 4) = o4;
    }
  }  // ph
}

// ---------------- launch ----------------
extern "C" void kernel_launch(void* const* d_in, const int* in_sizes, int n_in,
                              void* d_out, int out_size, void* d_ws, size_t ws_size,
                              hipStream_t stream) {
  const float* q  = (const float*)d_in[0];
  const float* k  = (const float*)d_in[1];
  const float* v  = (const float*)d_in[2];
  // d_in[3] = mask (int32 tril, implemented analytically)
  const float* Wq = (const float*)d_in[4];
  const float* bq = (const float*)d_in[5];
  const float* Wk = (const float*)d_in[6];
  const float* bk = (const float*)d_in[7];
  const float* Wv = (const float*)d_in[8];
  const float* bv = (const float*)d_in[9];
  const float* Wo = (const float*)d_in[10];
  const float* bo = (const float*)d_in[11];
  float* out = (float*)d_out;

  const size_t NX = (size_t)NB * NS * ND;  // 8388608
  const size_t NW = (size_t)ND * ND;       // 1048576
  char* ws = (char*)d_ws;
  size_t off = 0;
  auto alloc = [&](size_t bytes) {
    char* p = ws + off;
    off += (bytes + 255) & ~(size_t)255;
    return p;
  };
  bf16_t* wqb = (bf16_t*)alloc(NW * 2);
  bf16_t* wkb = (bf16_t*)alloc(NW * 2);
  bf16_t* wvb = (bf16_t*)alloc(NW * 2);
  bf16_t* wob = (bf16_t*)alloc(NW * 2);
  bf16_t* q1  = (bf16_t*)alloc(NX * 2);
  bf16_t* k1  = (bf16_t*)alloc(NX * 2);
  bf16_t* v1  = (bf16_t*)alloc(NX * 2);
  bf16_t* at  = (bf16_t*)alloc(NX * 2);

  dim3 blk(256);
  cvt4_kernel<<<dim3(128, 4), blk, 0, stream>>>(Wq, wqb, Wk, wkb, Wv, wvb, Wo, wob, (long)NW);

  gemm_qkv<<<dim3(768), dim3(512), 0, stream>>>(
      q, wqb, bq, q1, k, wkb, bk, k1, v, wvb, bv, v1);

  attn_kernel<<<dim3((NT / 2) * NH * NB), blk, 0, stream>>>(q1, k1, v1, at);

  gemm_bt<<<dim3(256), dim3(512), 0, stream>>>(at, wob, bo, out, NB * NS, ND, ND);
}